// Round 20
// baseline (162.832 us; speedup 1.0000x reference)
//
#include <hip/hip_runtime.h>
#include <hip/hip_bf16.h>
#include <math.h>

#define NB 2048
#define NC 8
#define NNEG 512

typedef __attribute__((ext_vector_type(8))) short bf16x8;
typedef __attribute__((ext_vector_type(4))) float f32x4;
typedef __attribute__((ext_vector_type(16))) float f32x16;

static __device__ __forceinline__ unsigned short f2b(float f) {
  __hip_bfloat16 h = __float2bfloat16(f);
  return *reinterpret_cast<unsigned short*>(&h);
}
// branchless round-to-nearest bf16 pair pack: low16 = bf16(a), high16 = bf16(b).
static __device__ __forceinline__ unsigned int pack_rn(float a, float b) {
  unsigned int ua = __float_as_uint(a) + 0x8000u;
  unsigned int ub = __float_as_uint(b) + 0x8000u;
  return __builtin_amdgcn_perm(ub, ua, 0x07060302u);
}
#define MF16(a, b, c) __builtin_amdgcn_mfma_f32_16x16x32_bf16((a), (b), (c), 0, 0, 0)

// ---- ws layout (float offsets) ----
#define WS_SSUM   0          // [8][32]
#define WS_SPROD  256        // [8][32][32]
#define WS_B1EFF  8448       // [8][512] f32
#define WS_Z      12544      // [2048][8][32] f32  (aliased as SprodP partials before k_main)
#define WS_POS    536832     // [2048] f32
#define WS_W1B    538880     // ushort [8][512][32]
#define WS_W2B    604416     // ushort [32][512]
#define WS_FCWB   612608     // ushort [32][1024]
#define WS_ZNB    628992     // ushort [2048][256] (bf16 Zn)
#define WS_SSUMP  891136     // [8][64][32] Ssum partials
// end: 907520 floats = 3.63 MB

// ---------------- K1: moments via MFMA, atomic-free, 8 waves/block ----------------
// 512 threads: doubles wave-level parallelism (16 waves/CU) and halves each wave's
// serial load->cvt->MFMA chain (8 chunks instead of 16).
__global__ __launch_bounds__(512) void k_stats(const float* __restrict__ x,
                        float* __restrict__ SsumP, float* __restrict__ SprodP) {
  int c = blockIdx.y;
  int t = threadIdx.x;
  int w = t >> 6, l = t & 63;
  int col = l & 31, half = l >> 5;
  f32x16 acc;
  #pragma unroll
  for (int r = 0; r < 16; ++r) acc[r] = 0.f;
  float ssum = 0.f;
  #pragma unroll 2
  for (int i = 0; i < 8; ++i) {
    int chunk = blockIdx.x * 64 + i * 8 + w;          // 16-row chunk of channel c
    int b = chunk >> 1;
    int sb = (chunk & 1) * 16 + half * 8;
    const float* base = x + ((size_t)(b * NC + c)) * 1024 + sb * 32 + col;
    float v0 = base[0],   v1 = base[32],  v2 = base[64],  v3 = base[96];
    float v4 = base[128], v5 = base[160], v6 = base[192], v7 = base[224];
    ssum += ((v0 + v1) + (v2 + v3)) + ((v4 + v5) + (v6 + v7));
    uint4 fq;
    fq.x = pack_rn(v0, v1); fq.y = pack_rn(v2, v3);
    fq.z = pack_rn(v4, v5); fq.w = pack_rn(v6, v7);
    bf16x8 f = __builtin_bit_cast(bf16x8, fq);
    acc = __builtin_amdgcn_mfma_f32_32x32x16_bf16(f, f, acc, 0, 0, 0);
  }
  __shared__ float pr[8][1024];
  __shared__ float sred[8][32];
  #pragma unroll
  for (int r = 0; r < 16; ++r) {
    int row = (r & 3) + 8 * (r >> 2) + 4 * half;
    pr[w][row * 32 + col] = acc[r];
  }
  float sv = ssum + __shfl_xor(ssum, 32);
  if (l < 32) sred[w][l] = sv;
  __syncthreads();
  #pragma unroll
  for (int p = 0; p < 2; ++p) {
    int cell = t + p * 512;
    SprodP[((size_t)(c * 64 + blockIdx.x)) * 1024 + cell] =
        ((pr[0][cell] + pr[1][cell]) + (pr[2][cell] + pr[3][cell])) +
        ((pr[4][cell] + pr[5][cell]) + (pr[6][cell] + pr[7][cell]));
  }
  if (t < 32)
    SsumP[(c * 64 + blockIdx.x) * 32 + t] =
        ((sred[0][t] + sred[1][t]) + (sred[2][t] + sred[3][t])) +
        ((sred[4][t] + sred[5][t]) + (sred[6][t] + sred[7][t]));
}

// ---------------- K1b: reduce partials -> Sprod, Ssum (wide grid, latency-hidden) --------
__global__ __launch_bounds__(256) void k_red(
    const float* __restrict__ SprodP, const float* __restrict__ SsumP,
    float* __restrict__ Sprod, float* __restrict__ Ssum) {
  int t = threadIdx.x;
  if (blockIdx.x < 256) {
    int g0 = blockIdx.x * 32;          // first global cell (c*1024+cell)
    int ci = t & 31, p = t >> 5;       // 32 cells x 8 p-groups
    int g = g0 + ci;
    int c = g >> 10, cell = g & 1023;
    float s = 0.f;
    #pragma unroll
    for (int k = 0; k < 8; ++k)
      s += SprodP[((size_t)(c * 64 + p + k * 8)) * 1024 + cell];
    __shared__ float red[256];
    red[t] = s;
    __syncthreads();
    if (t < 32) {
      float v = 0.f;
      #pragma unroll
      for (int pp = 0; pp < 8; ++pp) v += red[pp * 32 + t];
      Sprod[g0 + t] = v;
    }
  } else {
    int c = t >> 5, d = t & 31;        // 256 threads = all (c,d)
    float s = 0.f;
    #pragma unroll 8
    for (int p = 0; p < 64; ++p)
      s += SsumP[(c * 64 + p) * 32 + d];
    Ssum[t] = s;
  }
}

// ---------------- K2: fold BN into W1 (bf16, M staged in LDS) + convert W2/fcW -----------
__global__ __launch_bounds__(256) void k_foldcvt(
    const float* __restrict__ W1, const float* __restrict__ b1,
    const float* __restrict__ gamma, const float* __restrict__ beta,
    const float* __restrict__ Ssum, const float* __restrict__ Sprod,
    const float* __restrict__ W2, const float* __restrict__ fcW,
    unsigned short* __restrict__ W1B, float* __restrict__ b1eff,
    unsigned short* __restrict__ W2B, unsigned short* __restrict__ fcWB) {
  if (blockIdx.x >= 16) {
    int j = (blockIdx.x - 16) * 256 + threadIdx.x;   // pair index 0..16383
    if (j < 8192)
      ((unsigned int*)W2B)[j] = pack_rn(W2[2 * j], W2[2 * j + 1]);
    ((unsigned int*)fcWB)[j] = pack_rn(fcW[2 * j], fcW[2 * j + 1]);
    return;
  }
  int g = blockIdx.x * 256 + threadIdx.x;   // 0..4095
  int c = g >> 9, h = g & 511;
  int t = threadIdx.x;
  __shared__ float Ms[1024];
  #pragma unroll
  for (int p4 = 0; p4 < 4; ++p4)
    Ms[t + p4 * 256] = Sprod[c * 1024 + t + p4 * 256];
  __syncthreads();
  const float invN = 1.0f / (float)(NB * 32);
  float w[32];
  #pragma unroll
  for (int d = 0; d < 32; ++d) w[d] = W1[h * 32 + d];
  float q = 0.f;
  for (int j = 0; j < 32; ++j) {
    float v = 0.f;
    #pragma unroll
    for (int i2 = 0; i2 < 32; ++i2) v = fmaf(w[i2], Ms[i2 * 32 + j], v);
    q = fmaf(v, w[j], q);
  }
  float wmu = 0.f;
  #pragma unroll
  for (int d = 0; d < 32; ++d) wmu = fmaf(w[d], Ssum[c * 32 + d] * invN, wmu);
  float bb = b1[h];
  float mean = wmu + bb;
  float e2 = q * invN + 2.f * bb * wmu + bb * bb;
  float var = e2 - mean * mean;
  float alpha = gamma[h] * rsqrtf(var + 1e-5f);
  unsigned int* W1Bu = (unsigned int*)&W1B[((size_t)c * 512 + h) * 32];
  #pragma unroll
  for (int d = 0; d < 16; ++d)
    W1Bu[d] = pack_rn(w[2 * d] * alpha, w[2 * d + 1] * alpha);
  b1eff[c * 512 + h] = (bb - mean) * alpha + beta[h];
}

// ---------------- K3: fused 16x16 MFMA, persistent blocks (4 tiles each) ----------------
// R12/R14 kernel (measured 84 us) — UNCHANGED.
__global__ __launch_bounds__(256, 2) void k_main(
    const float* __restrict__ x, const unsigned short* __restrict__ W1B,
    const float* __restrict__ b1eff, const unsigned short* __restrict__ W2B,
    const float* __restrict__ b2, const unsigned short* __restrict__ fcWB,
    const float* __restrict__ fcb, float* __restrict__ Z) {
  int c = blockIdx.y;
  int bt0 = blockIdx.x * 4;       // 64 groups of 4 tiles (8 b each)
  int t = threadIdx.x;
  int w = t >> 6, l = t & 63;
  int lr = l & 15, lg = l >> 4;

  __shared__ unsigned int rbuf[4][64][20];   // 20 KB; wave-private [64 s][20 dw]
  __shared__ float zred[2][8][32];

  const unsigned short* W1c = W1B + (size_t)c * 512 * 32;
  const float* b1e = b1eff + c * 512;
  unsigned int* rbw = &rbuf[w][0][0];

  bf16x8 wfR[2];   f32x4 biasR[2];   bf16x8 w2fR[2];   bf16x8 hfreg[4];
  bf16x8 xf[4], xfN[4];

#define LOADX(dst, bti) \
  _Pragma("unroll") for (int sb = 0; sb < 4; ++sb) { \
    int bl = 2 * w + (sb >> 1); \
    int s = (sb & 1) * 16 + lr; \
    const float* src = x + (((size_t)((bti) * 8 + bl) * NC + c) * 32 + s) * 32 + lg * 8; \
    float4 v0 = ((const float4*)src)[0]; \
    float4 v1 = ((const float4*)src)[1]; \
    uint4 fq; \
    fq.x = pack_rn(v0.x, v0.y); fq.y = pack_rn(v0.z, v0.w); \
    fq.z = pack_rn(v1.x, v1.y); fq.w = pack_rn(v1.z, v1.w); \
    dst[sb] = __builtin_bit_cast(bf16x8, fq); \
  }

#define LDWF0() { \
    wfR[0]  = *(const bf16x8*)&W1c[(size_t)lr * 32 + lg * 8]; \
    wfR[1]  = *(const bf16x8*)&W1c[(size_t)(16 + lr) * 32 + lg * 8]; \
    biasR[0] = *(const f32x4*)(b1e + lg * 4); \
    biasR[1] = *(const f32x4*)(b1e + 16 + lg * 4); }

#define GEMM1(dfr) \
  _Pragma("unroll") for (int hb = 0; hb < 2; ++hb) \
  _Pragma("unroll") for (int sb = 0; sb < 4; ++sb) \
    dfr[hb][sb] = MF16(wfR[hb], xf[sb], biasR[hb]);

#define GEMM2() \
  _Pragma("unroll") for (int mb = 0; mb < 4; ++mb) { \
    yacc[mb][0] = MF16(w2fR[0], hfreg[mb], yacc[mb][0]); \
    yacc[mb][1] = MF16(w2fR[1], hfreg[mb], yacc[mb][1]); \
  }

#define PACKWRITE(dfr) \
  _Pragma("unroll") for (int hb = 0; hb < 2; ++hb) \
  _Pragma("unroll") for (int sb = 0; sb < 4; ++sb) { \
    uint2 pk; \
    pk.x = pack_rn(fmaxf(dfr[hb][sb][0], 0.f), fmaxf(dfr[hb][sb][1], 0.f)); \
    pk.y = pack_rn(fmaxf(dfr[hb][sb][2], 0.f), fmaxf(dfr[hb][sb][3], 0.f)); \
    *(uint2*)&rbw[(sb * 16 + lr) * 20 + hb * 8 + lg * 2] = pk; \
  }

#define LOADW(ch) { \
    if ((ch) < 15) { \
      int h1 = ((ch) + 1) * 32; \
      wfR[0]  = *(const bf16x8*)&W1c[(size_t)(h1 + lr) * 32 + lg * 8]; \
      wfR[1]  = *(const bf16x8*)&W1c[(size_t)(h1 + 16 + lr) * 32 + lg * 8]; \
      biasR[0] = *(const f32x4*)(b1e + h1 + lg * 4); \
      biasR[1] = *(const f32x4*)(b1e + h1 + 16 + lg * 4); \
    } \
    w2fR[0] = *(const bf16x8*)&W2B[(size_t)lr * 512 + (ch) * 32 + lg * 8]; \
    w2fR[1] = *(const bf16x8*)&W2B[(size_t)(16 + lr) * 512 + (ch) * 32 + lg * 8]; \
  }

#define READH() \
  _Pragma("unroll") for (int mb = 0; mb < 4; ++mb) \
    hfreg[mb] = *(const bf16x8*)&rbw[(mb * 16 + lr) * 20 + lg * 4];

  LOADX(xf, bt0);    // tile 0 x
  LDWF0();           // ch0 weights

  for (int tt = 0; tt < 4; ++tt) {
    int bt = bt0 + tt;

    f32x4 yacc[4][2];
    #pragma unroll
    for (int db = 0; db < 2; ++db) {
      f32x4 bv = *((const f32x4*)(b2 + db * 16 + lg * 4));
      #pragma unroll
      for (int mb = 0; mb < 4; ++mb) yacc[mb][db] = bv;
    }

    {  // prologue: ch = 0
      f32x4 dfr[2][4];
      GEMM1(dfr);
      PACKWRITE(dfr);
      LOADW(0);
      READH();
    }
    #pragma unroll 3
    for (int ch = 1; ch < 16; ++ch) {
      f32x4 dfr[2][4];
      GEMM1(dfr);      // chunk ch (weights prefetched last iter)
      GEMM2();         // chunk ch-1
      PACKWRITE(dfr);  // chunk ch
      LOADW(ch);       // wf/bias for ch+1, w2f for ch
      READH();         // chunk ch, consumed next iter
    }
    GEMM2();           // epilogue: chunk 15

    if (tt < 3) LOADX(xfN, bt + 1);
    LDWF0();

    #pragma unroll
    for (int mb = 0; mb < 4; ++mb) {
      #pragma unroll
      for (int db = 0; db < 2; ++db) {
        uint2 pk;
        pk.x = pack_rn(yacc[mb][db][0], yacc[mb][db][1]);
        pk.y = pack_rn(yacc[mb][db][2], yacc[mb][db][3]);
        *(uint2*)&rbw[(mb * 16 + lr) * 20 + db * 8 + lg * 2] = pk;
      }
    }
    __syncthreads();

    {
      int nt = w & 1, kh = w >> 1;
      int arow = (lr < 8) ? lr : 7;
      const unsigned int* ybase = &rbuf[arow >> 1][(arow & 1) * 32][0];
      f32x4 zacc = {0.f, 0.f, 0.f, 0.f};
      #pragma unroll
      for (int ks = 0; ks < 16; ++ks) {
        int s = kh * 16 + ks;
        uint4 av = *(const uint4*)&ybase[s * 20 + lg * 4];
        bf16x8 afc = __builtin_bit_cast(bf16x8, av);
        bf16x8 bfc = *(const bf16x8*)&fcWB[(size_t)(nt * 16 + lr) * 1024 + s * 32 + lg * 8];
        zacc = MF16(afc, bfc, zacc);
      }
      if (lg < 2) {
        #pragma unroll
        for (int r = 0; r < 4; ++r) zred[kh][lg * 4 + r][nt * 16 + lr] = zacc[r];
      }
    }
    __syncthreads();
    {
      int bloc = t >> 5, o = t & 31;
      Z[((size_t)(bt * 8 + bloc) * NC + c) * 32 + o] =
          zred[0][bloc][o] + zred[1][bloc][o] + fcb[o];
    }
    if (tt < 3) {
      #pragma unroll
      for (int sb = 0; sb < 4; ++sb) xf[sb] = xfN[sb];
    }
  }
#undef LOADX
#undef LDWF0
#undef GEMM1
#undef GEMM2
#undef PACKWRITE
#undef LOADW
#undef READH
}

// ---------------- K4: normalize -> bf16 Zn, pos_sim, Z_out (R14 form) ----------------
__global__ void k_znorm(const float* __restrict__ Z, unsigned short* __restrict__ Znb,
                        float* __restrict__ possim, float* __restrict__ out) {
  int b = blockIdx.x;
  int t = threadIdx.x;        // 256: t = c*32 + d
  float v = Z[(size_t)b * 256 + t];
  float n2 = v * v;
  #pragma unroll
  for (int m = 16; m >= 1; m >>= 1) n2 += __shfl_xor(n2, m, 64);
  float nrm = fmaxf(sqrtf(n2), 1e-8f);
  float zn = v / nrm;
  Znb[(size_t)b * 256 + t] = f2b(zn);
  __shared__ float sz[256];
  __shared__ float szn[256];
  sz[t] = v; szn[t] = zn;
  __syncthreads();
  if (t < 32) {
    float s = 0.f;
    #pragma unroll
    for (int cc = 0; cc < 8; ++cc) s += sz[cc * 32 + t];
    out[(size_t)b * 32 + t] = s * 0.125f;
    float sd = 0.f, t1 = 0.f;
    #pragma unroll
    for (int cc = 0; cc < 8; ++cc) {
      float z2 = szn[cc * 32 + t];
      sd += z2; t1 = fmaf(z2, z2, t1);
    }
    float t2 = sd * sd;
    #pragma unroll
    for (int m = 16; m >= 1; m >>= 1) {
      t2 += __shfl_xor(t2, m, 64);
      t1 += __shfl_xor(t1, m, 64);
    }
    if (t == 0) possim[b] = (t2 - t1) * 0.5f / 28.0f;
  }
}

// ---------------- K5: negative-sim via gathered-A MFMA (R16 form) ----------------
__global__ __launch_bounds__(256) void k_negsim(
    const unsigned short* __restrict__ Znb, const int* __restrict__ neg_idx,
    const float* __restrict__ possim, float* __restrict__ lout) {
  int b = blockIdx.x;
  int t = threadIdx.x;   // 256 = 4 waves
  int w = t >> 6, l = t & 63;
  int lr = l & 15, lg = l >> 4;
  __shared__ uint4 selfv[32];
  __shared__ float rs[4];
  if (t < 32) selfv[t] = ((const uint4*)(Znb + (size_t)b * 256))[t];
  __syncthreads();
  const unsigned short* selfp = (const unsigned short*)selfv;
  bf16x8 sf[8];
  #pragma unroll
  for (int ks = 0; ks < 8; ++ks) sf[ks] = *(const bf16x8*)(selfp + ks * 32 + lg * 8);
  const f32x4 fzero = {0.f, 0.f, 0.f, 0.f};
  float esum = 0.f;
  #pragma unroll
  for (int mb = 0; mb < 8; ++mb) {
    int raw = neg_idx[(size_t)b * NNEG + w * 128 + mb * 16 + lr];
    int j = raw + (raw >= b ? 1 : 0);
    const unsigned short* rp = Znb + (size_t)j * 256;
    f32x4 acc0 = fzero, acc1 = fzero;
    #pragma unroll
    for (int ks = 0; ks < 4; ++ks) {
      acc0 = MF16(*(const bf16x8*)(rp + ks * 32 + lg * 8), sf[ks], acc0);
      acc1 = MF16(*(const bf16x8*)(rp + (ks + 4) * 32 + lg * 8), sf[ks + 4], acc1);
    }
    if (lr == 0) {
      esum += expf((acc0[0] + acc1[0]) * 0.25f) + expf((acc0[1] + acc1[1]) * 0.25f)
            + expf((acc0[2] + acc1[2]) * 0.25f) + expf((acc0[3] + acc1[3]) * 0.25f);
    }
  }
  #pragma unroll
  for (int m = 32; m >= 1; m >>= 1) esum += __shfl_xor(esum, m, 64);
  if (l == 0) rs[w] = esum;
  __syncthreads();
  if (t == 0) {
    float tot = rs[0] + rs[1] + rs[2] + rs[3];
    lout[b] = expf(possim[b] * 2.0f) / tot;
  }
}

extern "C" void kernel_launch(void* const* d_in, const int* in_sizes, int n_in,
                              void* d_out, int out_size, void* d_ws, size_t ws_size,
                              hipStream_t stream) {
  const float* x     = (const float*)d_in[0];
  const float* W1    = (const float*)d_in[1];
  const float* b1    = (const float*)d_in[2];
  const float* gamma = (const float*)d_in[3];
  const float* beta  = (const float*)d_in[4];
  const float* W2    = (const float*)d_in[5];
  const float* b2    = (const float*)d_in[6];
  const float* fcW   = (const float*)d_in[7];
  const float* fcb   = (const float*)d_in[8];
  const int*   nidx  = (const int*)d_in[9];
  float* ws = (float*)d_ws;
  float* Ssum   = ws + WS_SSUM;
  float* Sprod  = ws + WS_SPROD;
  float* b1eff  = ws + WS_B1EFF;
  float* Z      = ws + WS_Z;
  float* SprodP = ws + WS_Z;       // partials alias Z (serial: stats->red->main)
  float* SsumP  = ws + WS_SSUMP;
  float* possim = ws + WS_POS;
  unsigned short* W1Bp  = (unsigned short*)(ws + WS_W1B);
  unsigned short* W2Bp  = (unsigned short*)(ws + WS_W2B);
  unsigned short* fcWBp = (unsigned short*)(ws + WS_FCWB);
  unsigned short* Znbp  = (unsigned short*)(ws + WS_ZNB);
  float* out = (float*)d_out;

  k_stats<<<dim3(64, 8), 512, 0, stream>>>(x, SsumP, SprodP);
  k_red<<<257, 256, 0, stream>>>(SprodP, SsumP, Sprod, Ssum);
  k_foldcvt<<<80, 256, 0, stream>>>(W1, b1, gamma, beta, Ssum, Sprod, W2, fcW,
                                    W1Bp, b1eff, W2Bp, fcWBp);
  k_main<<<dim3(64, 8), 256, 0, stream>>>(x, W1Bp, b1eff, W2Bp, b2, fcWBp, fcb, Z);
  k_znorm<<<NB, 256, 0, stream>>>(Z, Znbp, possim, out);
  k_negsim<<<NB, 256, 0, stream>>>(Znbp, nidx, possim, out + NB * 32);
}

// Round 21
// 162.130 us; speedup vs baseline: 1.0043x; 1.0043x over previous
//
#include <hip/hip_runtime.h>
#include <hip/hip_bf16.h>
#include <math.h>

#define NB 2048
#define NC 8
#define NNEG 512

typedef __attribute__((ext_vector_type(8))) short bf16x8;
typedef __attribute__((ext_vector_type(4))) float f32x4;
typedef __attribute__((ext_vector_type(16))) float f32x16;

static __device__ __forceinline__ unsigned short f2b(float f) {
  __hip_bfloat16 h = __float2bfloat16(f);
  return *reinterpret_cast<unsigned short*>(&h);
}
// branchless round-to-nearest bf16 pair pack: low16 = bf16(a), high16 = bf16(b).
static __device__ __forceinline__ unsigned int pack_rn(float a, float b) {
  unsigned int ua = __float_as_uint(a) + 0x8000u;
  unsigned int ub = __float_as_uint(b) + 0x8000u;
  return __builtin_amdgcn_perm(ub, ua, 0x07060302u);
}
#define MF16(a, b, c) __builtin_amdgcn_mfma_f32_16x16x32_bf16((a), (b), (c), 0, 0, 0)

// ---- ws layout (float offsets) ----
#define WS_SSUM   0          // [8][32]
#define WS_SPROD  256        // [8][32][32]
#define WS_B1EFF  8448       // [8][512] f32
#define WS_Z      12544      // [2048][8][32] f32  (aliased as SprodP partials before k_main)
#define WS_POS    536832     // [2048] f32
#define WS_W1B    538880     // ushort [8][512][32]
#define WS_W2B    604416     // ushort [32][512]
#define WS_FCWB   612608     // ushort [32][1024]
#define WS_ZNB    628992     // ushort [2048][256] (bf16 Zn)
#define WS_SSUMP  891136     // [8][64][32] Ssum partials
// end: 907520 floats = 3.63 MB

// ---------------- K1: moments via MFMA, atomic-free (per-block partials) ----------------
__global__ __launch_bounds__(256) void k_stats(const float* __restrict__ x,
                        float* __restrict__ SsumP, float* __restrict__ SprodP) {
  int c = blockIdx.y;
  int t = threadIdx.x;
  int w = t >> 6, l = t & 63;
  int col = l & 31, half = l >> 5;
  f32x16 acc;
  #pragma unroll
  for (int r = 0; r < 16; ++r) acc[r] = 0.f;
  float ssum = 0.f;
  #pragma unroll 2
  for (int i = 0; i < 16; ++i) {
    int chunk = blockIdx.x * 64 + i * 4 + w;          // 16-row chunk of channel c
    int b = chunk >> 1;
    int sb = (chunk & 1) * 16 + half * 8;
    const float* base = x + ((size_t)(b * NC + c)) * 1024 + sb * 32 + col;
    float v0 = base[0],   v1 = base[32],  v2 = base[64],  v3 = base[96];
    float v4 = base[128], v5 = base[160], v6 = base[192], v7 = base[224];
    ssum += ((v0 + v1) + (v2 + v3)) + ((v4 + v5) + (v6 + v7));
    uint4 fq;
    fq.x = pack_rn(v0, v1); fq.y = pack_rn(v2, v3);
    fq.z = pack_rn(v4, v5); fq.w = pack_rn(v6, v7);
    bf16x8 f = __builtin_bit_cast(bf16x8, fq);
    acc = __builtin_amdgcn_mfma_f32_32x32x16_bf16(f, f, acc, 0, 0, 0);
  }
  __shared__ float pr[4][1024];
  __shared__ float sred[4][32];
  #pragma unroll
  for (int r = 0; r < 16; ++r) {
    int row = (r & 3) + 8 * (r >> 2) + 4 * half;
    pr[w][row * 32 + col] = acc[r];
  }
  float sv = ssum + __shfl_xor(ssum, 32);
  if (l < 32) sred[w][l] = sv;
  __syncthreads();
  #pragma unroll
  for (int p = 0; p < 4; ++p) {
    int cell = t + p * 256;
    SprodP[((size_t)(c * 64 + blockIdx.x)) * 1024 + cell] =
        (pr[0][cell] + pr[1][cell]) + (pr[2][cell] + pr[3][cell]);
  }
  if (t < 32)
    SsumP[(c * 64 + blockIdx.x) * 32 + t] =
        (sred[0][t] + sred[1][t]) + (sred[2][t] + sred[3][t]);
}

// ---------------- K1b: reduce partials -> Sprod, Ssum (wide grid, latency-hidden) --------
__global__ __launch_bounds__(256) void k_red(
    const float* __restrict__ SprodP, const float* __restrict__ SsumP,
    float* __restrict__ Sprod, float* __restrict__ Ssum) {
  int t = threadIdx.x;
  if (blockIdx.x < 256) {
    int g0 = blockIdx.x * 32;          // first global cell (c*1024+cell)
    int ci = t & 31, p = t >> 5;       // 32 cells x 8 p-groups
    int g = g0 + ci;
    int c = g >> 10, cell = g & 1023;
    float s = 0.f;
    #pragma unroll
    for (int k = 0; k < 8; ++k)
      s += SprodP[((size_t)(c * 64 + p + k * 8)) * 1024 + cell];
    __shared__ float red[256];
    red[t] = s;
    __syncthreads();
    if (t < 32) {
      float v = 0.f;
      #pragma unroll
      for (int pp = 0; pp < 8; ++pp) v += red[pp * 32 + t];
      Sprod[g0 + t] = v;
    }
  } else {
    int c = t >> 5, d = t & 31;        // 256 threads = all (c,d)
    float s = 0.f;
    #pragma unroll 8
    for (int p = 0; p < 64; ++p)
      s += SsumP[(c * 64 + p) * 32 + d];
    Ssum[t] = s;
  }
}

// ---------------- K2: fold BN into W1 (bf16, M staged in LDS) + convert W2/fcW -----------
__global__ __launch_bounds__(256) void k_foldcvt(
    const float* __restrict__ W1, const float* __restrict__ b1,
    const float* __restrict__ gamma, const float* __restrict__ beta,
    const float* __restrict__ Ssum, const float* __restrict__ Sprod,
    const float* __restrict__ W2, const float* __restrict__ fcW,
    unsigned short* __restrict__ W1B, float* __restrict__ b1eff,
    unsigned short* __restrict__ W2B, unsigned short* __restrict__ fcWB) {
  if (blockIdx.x >= 16) {
    int j = (blockIdx.x - 16) * 256 + threadIdx.x;   // pair index 0..16383
    if (j < 8192)
      ((unsigned int*)W2B)[j] = pack_rn(W2[2 * j], W2[2 * j + 1]);
    ((unsigned int*)fcWB)[j] = pack_rn(fcW[2 * j], fcW[2 * j + 1]);
    return;
  }
  int g = blockIdx.x * 256 + threadIdx.x;   // 0..4095
  int c = g >> 9, h = g & 511;
  int t = threadIdx.x;
  __shared__ float Ms[1024];
  #pragma unroll
  for (int p4 = 0; p4 < 4; ++p4)
    Ms[t + p4 * 256] = Sprod[c * 1024 + t + p4 * 256];
  __syncthreads();
  const float invN = 1.0f / (float)(NB * 32);
  float w[32];
  #pragma unroll
  for (int d = 0; d < 32; ++d) w[d] = W1[h * 32 + d];
  float q = 0.f;
  for (int j = 0; j < 32; ++j) {
    float v = 0.f;
    #pragma unroll
    for (int i2 = 0; i2 < 32; ++i2) v = fmaf(w[i2], Ms[i2 * 32 + j], v);
    q = fmaf(v, w[j], q);
  }
  float wmu = 0.f;
  #pragma unroll
  for (int d = 0; d < 32; ++d) wmu = fmaf(w[d], Ssum[c * 32 + d] * invN, wmu);
  float bb = b1[h];
  float mean = wmu + bb;
  float e2 = q * invN + 2.f * bb * wmu + bb * bb;
  float var = e2 - mean * mean;
  float alpha = gamma[h] * rsqrtf(var + 1e-5f);
  unsigned int* W1Bu = (unsigned int*)&W1B[((size_t)c * 512 + h) * 32];
  #pragma unroll
  for (int d = 0; d < 16; ++d)
    W1Bu[d] = pack_rn(w[2 * d] * alpha, w[2 * d + 1] * alpha);
  b1eff[c * 512 + h] = (bb - mean) * alpha + beta[h];
}

// ---------------- K3: fused 16x16 MFMA, persistent blocks (4 tiles each) ----------------
// R12/R14 kernel (measured 84 us) — UNCHANGED.
__global__ __launch_bounds__(256, 2) void k_main(
    const float* __restrict__ x, const unsigned short* __restrict__ W1B,
    const float* __restrict__ b1eff, const unsigned short* __restrict__ W2B,
    const float* __restrict__ b2, const unsigned short* __restrict__ fcWB,
    const float* __restrict__ fcb, float* __restrict__ Z) {
  int c = blockIdx.y;
  int bt0 = blockIdx.x * 4;       // 64 groups of 4 tiles (8 b each)
  int t = threadIdx.x;
  int w = t >> 6, l = t & 63;
  int lr = l & 15, lg = l >> 4;

  __shared__ unsigned int rbuf[4][64][20];   // 20 KB; wave-private [64 s][20 dw]
  __shared__ float zred[2][8][32];

  const unsigned short* W1c = W1B + (size_t)c * 512 * 32;
  const float* b1e = b1eff + c * 512;
  unsigned int* rbw = &rbuf[w][0][0];

  bf16x8 wfR[2];   f32x4 biasR[2];   bf16x8 w2fR[2];   bf16x8 hfreg[4];
  bf16x8 xf[4], xfN[4];

#define LOADX(dst, bti) \
  _Pragma("unroll") for (int sb = 0; sb < 4; ++sb) { \
    int bl = 2 * w + (sb >> 1); \
    int s = (sb & 1) * 16 + lr; \
    const float* src = x + (((size_t)((bti) * 8 + bl) * NC + c) * 32 + s) * 32 + lg * 8; \
    float4 v0 = ((const float4*)src)[0]; \
    float4 v1 = ((const float4*)src)[1]; \
    uint4 fq; \
    fq.x = pack_rn(v0.x, v0.y); fq.y = pack_rn(v0.z, v0.w); \
    fq.z = pack_rn(v1.x, v1.y); fq.w = pack_rn(v1.z, v1.w); \
    dst[sb] = __builtin_bit_cast(bf16x8, fq); \
  }

#define LDWF0() { \
    wfR[0]  = *(const bf16x8*)&W1c[(size_t)lr * 32 + lg * 8]; \
    wfR[1]  = *(const bf16x8*)&W1c[(size_t)(16 + lr) * 32 + lg * 8]; \
    biasR[0] = *(const f32x4*)(b1e + lg * 4); \
    biasR[1] = *(const f32x4*)(b1e + 16 + lg * 4); }

#define GEMM1(dfr) \
  _Pragma("unroll") for (int hb = 0; hb < 2; ++hb) \
  _Pragma("unroll") for (int sb = 0; sb < 4; ++sb) \
    dfr[hb][sb] = MF16(wfR[hb], xf[sb], biasR[hb]);

#define GEMM2() \
  _Pragma("unroll") for (int mb = 0; mb < 4; ++mb) { \
    yacc[mb][0] = MF16(w2fR[0], hfreg[mb], yacc[mb][0]); \
    yacc[mb][1] = MF16(w2fR[1], hfreg[mb], yacc[mb][1]); \
  }

#define PACKWRITE(dfr) \
  _Pragma("unroll") for (int hb = 0; hb < 2; ++hb) \
  _Pragma("unroll") for (int sb = 0; sb < 4; ++sb) { \
    uint2 pk; \
    pk.x = pack_rn(fmaxf(dfr[hb][sb][0], 0.f), fmaxf(dfr[hb][sb][1], 0.f)); \
    pk.y = pack_rn(fmaxf(dfr[hb][sb][2], 0.f), fmaxf(dfr[hb][sb][3], 0.f)); \
    *(uint2*)&rbw[(sb * 16 + lr) * 20 + hb * 8 + lg * 2] = pk; \
  }

#define LOADW(ch) { \
    if ((ch) < 15) { \
      int h1 = ((ch) + 1) * 32; \
      wfR[0]  = *(const bf16x8*)&W1c[(size_t)(h1 + lr) * 32 + lg * 8]; \
      wfR[1]  = *(const bf16x8*)&W1c[(size_t)(h1 + 16 + lr) * 32 + lg * 8]; \
      biasR[0] = *(const f32x4*)(b1e + h1 + lg * 4); \
      biasR[1] = *(const f32x4*)(b1e + h1 + 16 + lg * 4); \
    } \
    w2fR[0] = *(const bf16x8*)&W2B[(size_t)lr * 512 + (ch) * 32 + lg * 8]; \
    w2fR[1] = *(const bf16x8*)&W2B[(size_t)(16 + lr) * 512 + (ch) * 32 + lg * 8]; \
  }

#define READH() \
  _Pragma("unroll") for (int mb = 0; mb < 4; ++mb) \
    hfreg[mb] = *(const bf16x8*)&rbw[(mb * 16 + lr) * 20 + lg * 4];

  LOADX(xf, bt0);    // tile 0 x
  LDWF0();           // ch0 weights

  for (int tt = 0; tt < 4; ++tt) {
    int bt = bt0 + tt;

    f32x4 yacc[4][2];
    #pragma unroll
    for (int db = 0; db < 2; ++db) {
      f32x4 bv = *((const f32x4*)(b2 + db * 16 + lg * 4));
      #pragma unroll
      for (int mb = 0; mb < 4; ++mb) yacc[mb][db] = bv;
    }

    {  // prologue: ch = 0
      f32x4 dfr[2][4];
      GEMM1(dfr);
      PACKWRITE(dfr);
      LOADW(0);
      READH();
    }
    #pragma unroll 3
    for (int ch = 1; ch < 16; ++ch) {
      f32x4 dfr[2][4];
      GEMM1(dfr);      // chunk ch (weights prefetched last iter)
      GEMM2();         // chunk ch-1
      PACKWRITE(dfr);  // chunk ch
      LOADW(ch);       // wf/bias for ch+1, w2f for ch
      READH();         // chunk ch, consumed next iter
    }
    GEMM2();           // epilogue: chunk 15

    if (tt < 3) LOADX(xfN, bt + 1);
    LDWF0();

    #pragma unroll
    for (int mb = 0; mb < 4; ++mb) {
      #pragma unroll
      for (int db = 0; db < 2; ++db) {
        uint2 pk;
        pk.x = pack_rn(yacc[mb][db][0], yacc[mb][db][1]);
        pk.y = pack_rn(yacc[mb][db][2], yacc[mb][db][3]);
        *(uint2*)&rbw[(mb * 16 + lr) * 20 + db * 8 + lg * 2] = pk;
      }
    }
    __syncthreads();

    {
      int nt = w & 1, kh = w >> 1;
      int arow = (lr < 8) ? lr : 7;
      const unsigned int* ybase = &rbuf[arow >> 1][(arow & 1) * 32][0];
      f32x4 zacc = {0.f, 0.f, 0.f, 0.f};
      #pragma unroll
      for (int ks = 0; ks < 16; ++ks) {
        int s = kh * 16 + ks;
        uint4 av = *(const uint4*)&ybase[s * 20 + lg * 4];
        bf16x8 afc = __builtin_bit_cast(bf16x8, av);
        bf16x8 bfc = *(const bf16x8*)&fcWB[(size_t)(nt * 16 + lr) * 1024 + s * 32 + lg * 8];
        zacc = MF16(afc, bfc, zacc);
      }
      if (lg < 2) {
        #pragma unroll
        for (int r = 0; r < 4; ++r) zred[kh][lg * 4 + r][nt * 16 + lr] = zacc[r];
      }
    }
    __syncthreads();
    {
      int bloc = t >> 5, o = t & 31;
      Z[((size_t)(bt * 8 + bloc) * NC + c) * 32 + o] =
          zred[0][bloc][o] + zred[1][bloc][o] + fcb[o];
    }
    if (tt < 3) {
      #pragma unroll
      for (int sb = 0; sb < 4; ++sb) xf[sb] = xfN[sb];
    }
  }
#undef LOADX
#undef LDWF0
#undef GEMM1
#undef GEMM2
#undef PACKWRITE
#undef LOADW
#undef READH
}

// ---------------- K4: normalize -> bf16 Zn, pos_sim, Z_out (R14 form) ----------------
__global__ void k_znorm(const float* __restrict__ Z, unsigned short* __restrict__ Znb,
                        float* __restrict__ possim, float* __restrict__ out) {
  int b = blockIdx.x;
  int t = threadIdx.x;        // 256: t = c*32 + d
  float v = Z[(size_t)b * 256 + t];
  float n2 = v * v;
  #pragma unroll
  for (int m = 16; m >= 1; m >>= 1) n2 += __shfl_xor(n2, m, 64);
  float nrm = fmaxf(sqrtf(n2), 1e-8f);
  float zn = v / nrm;
  Znb[(size_t)b * 256 + t] = f2b(zn);
  __shared__ float sz[256];
  __shared__ float szn[256];
  sz[t] = v; szn[t] = zn;
  __syncthreads();
  if (t < 32) {
    float s = 0.f;
    #pragma unroll
    for (int cc = 0; cc < 8; ++cc) s += sz[cc * 32 + t];
    out[(size_t)b * 32 + t] = s * 0.125f;
    float sd = 0.f, t1 = 0.f;
    #pragma unroll
    for (int cc = 0; cc < 8; ++cc) {
      float z2 = szn[cc * 32 + t];
      sd += z2; t1 = fmaf(z2, z2, t1);
    }
    float t2 = sd * sd;
    #pragma unroll
    for (int m = 16; m >= 1; m >>= 1) {
      t2 += __shfl_xor(t2, m, 64);
      t1 += __shfl_xor(t1, m, 64);
    }
    if (t == 0) possim[b] = (t2 - t1) * 0.5f / 28.0f;
  }
}

// ---------------- K5: negative-sim via gathered-A MFMA (R16 form) ----------------
__global__ __launch_bounds__(256) void k_negsim(
    const unsigned short* __restrict__ Znb, const int* __restrict__ neg_idx,
    const float* __restrict__ possim, float* __restrict__ lout) {
  int b = blockIdx.x;
  int t = threadIdx.x;   // 256 = 4 waves
  int w = t >> 6, l = t & 63;
  int lr = l & 15, lg = l >> 4;
  __shared__ uint4 selfv[32];
  __shared__ float rs[4];
  if (t < 32) selfv[t] = ((const uint4*)(Znb + (size_t)b * 256))[t];
  __syncthreads();
  const unsigned short* selfp = (const unsigned short*)selfv;
  bf16x8 sf[8];
  #pragma unroll
  for (int ks = 0; ks < 8; ++ks) sf[ks] = *(const bf16x8*)(selfp + ks * 32 + lg * 8);
  const f32x4 fzero = {0.f, 0.f, 0.f, 0.f};
  float esum = 0.f;
  #pragma unroll
  for (int mb = 0; mb < 8; ++mb) {
    int raw = neg_idx[(size_t)b * NNEG + w * 128 + mb * 16 + lr];
    int j = raw + (raw >= b ? 1 : 0);
    const unsigned short* rp = Znb + (size_t)j * 256;
    f32x4 acc0 = fzero, acc1 = fzero;
    #pragma unroll
    for (int ks = 0; ks < 4; ++ks) {
      acc0 = MF16(*(const bf16x8*)(rp + ks * 32 + lg * 8), sf[ks], acc0);
      acc1 = MF16(*(const bf16x8*)(rp + (ks + 4) * 32 + lg * 8), sf[ks + 4], acc1);
    }
    if (lr == 0) {
      esum += expf((acc0[0] + acc1[0]) * 0.25f) + expf((acc0[1] + acc1[1]) * 0.25f)
            + expf((acc0[2] + acc1[2]) * 0.25f) + expf((acc0[3] + acc1[3]) * 0.25f);
    }
  }
  #pragma unroll
  for (int m = 32; m >= 1; m >>= 1) esum += __shfl_xor(esum, m, 64);
  if (l == 0) rs[w] = esum;
  __syncthreads();
  if (t == 0) {
    float tot = rs[0] + rs[1] + rs[2] + rs[3];
    lout[b] = expf(possim[b] * 2.0f) / tot;
  }
}

extern "C" void kernel_launch(void* const* d_in, const int* in_sizes, int n_in,
                              void* d_out, int out_size, void* d_ws, size_t ws_size,
                              hipStream_t stream) {
  const float* x     = (const float*)d_in[0];
  const float* W1    = (const float*)d_in[1];
  const float* b1    = (const float*)d_in[2];
  const float* gamma = (const float*)d_in[3];
  const float* beta  = (const float*)d_in[4];
  const float* W2    = (const float*)d_in[5];
  const float* b2    = (const float*)d_in[6];
  const float* fcW   = (const float*)d_in[7];
  const float* fcb   = (const float*)d_in[8];
  const int*   nidx  = (const int*)d_in[9];
  float* ws = (float*)d_ws;
  float* Ssum   = ws + WS_SSUM;
  float* Sprod  = ws + WS_SPROD;
  float* b1eff  = ws + WS_B1EFF;
  float* Z      = ws + WS_Z;
  float* SprodP = ws + WS_Z;       // partials alias Z (serial: stats->red->main)
  float* SsumP  = ws + WS_SSUMP;
  float* possim = ws + WS_POS;
  unsigned short* W1Bp  = (unsigned short*)(ws + WS_W1B);
  unsigned short* W2Bp  = (unsigned short*)(ws + WS_W2B);
  unsigned short* fcWBp = (unsigned short*)(ws + WS_FCWB);
  unsigned short* Znbp  = (unsigned short*)(ws + WS_ZNB);
  float* out = (float*)d_out;

  k_stats<<<dim3(64, 8), 256, 0, stream>>>(x, SsumP, SprodP);
  k_red<<<257, 256, 0, stream>>>(SprodP, SsumP, Sprod, Ssum);
  k_foldcvt<<<80, 256, 0, stream>>>(W1, b1, gamma, beta, Ssum, Sprod, W2, fcW,
                                    W1Bp, b1eff, W2Bp, fcWBp);
  k_main<<<dim3(64, 8), 256, 0, stream>>>(x, W1Bp, b1eff, W2Bp, b2, fcWBp, fcb, Z);
  k_znorm<<<NB, 256, 0, stream>>>(Z, Znbp, possim, out);
  k_negsim<<<NB, 256, 0, stream>>>(Znbp, nidx, possim, out + NB * 32);
}